// Round 8
// baseline (314.739 us; speedup 1.0000x reference)
//
#include <hip/hip_runtime.h>
#include <math.h>

#define BSZ 32
#define CH  256

typedef short  bf16x8 __attribute__((ext_vector_type(8)));
typedef float  f32x4  __attribute__((ext_vector_type(4)));
typedef unsigned short ushort_t;
typedef unsigned int   uint_t;

#define MFMA(a, b, c) __builtin_amdgcn_mfma_f32_16x16x32_bf16((a), (b), (c), 0, 0, 0)

__device__ __forceinline__ ushort_t f2b(float f) {
    uint_t u = __builtin_bit_cast(uint_t, f);
    uint_t r = (u + 0x7FFFu + ((u >> 16) & 1u)) >> 16;   // RTNE
    return (ushort_t)r;
}
__device__ __forceinline__ float b2f(ushort_t u) {
    uint_t v = ((uint_t)u) << 16;
    return __builtin_bit_cast(float, v);
}
__device__ __forceinline__ uint_t pk2(float a, float b) {
    return (uint_t)f2b(a) | ((uint_t)f2b(b) << 16);
}
__device__ __forceinline__ bf16x8 u4b8(uint4 u) {
    return __builtin_bit_cast(bf16x8, u);
}

// ---------------- kernel 1: per-cell winning edge (last write wins) -------
__global__ void edge_win_kernel(const int* __restrict__ ei, int E, int nb,
                                int* __restrict__ win) {
    int e = blockIdx.x * blockDim.x + threadIdx.x;
    if (e >= E) return;
    int r = ei[e];
    int c = ei[E + e];
    int br = r >> 5, bc = c >> 5;
    if (br == bc && br < nb) {
        atomicMax(&win[br * (BSZ * BSZ) + (r & 31) * BSZ + (c & 31)], e);
    }
}

// ---------------- kernel 1b: winning edges scatter their features ---------
// cellinfo[cell] = 4 bf16 {dx,dy,dz,val}; non-winners stay 0xFFFF (NaN).
__global__ void edge_feat_kernel(const int* __restrict__ ei,
                                 const float* __restrict__ ev,
                                 const float* __restrict__ pos,
                                 const int* __restrict__ win, int E,
                                 ushort_t* __restrict__ cellinfo) {
    int e = blockIdx.x * blockDim.x + threadIdx.x;
    if (e >= E) return;
    int r = ei[e];
    int c = ei[E + e];
    int br = r >> 5, bc = c >> 5;
    if (br != bc) return;
    int cell = br * 1024 + (r & 31) * 32 + (c & 31);
    if (win[cell] != e) return;
    float d0 = pos[c * 3 + 0] - pos[r * 3 + 0];
    float d1 = pos[c * 3 + 1] - pos[r * 3 + 1];
    float d2 = pos[c * 3 + 2] - pos[r * 3 + 2];
    float d3 = ev[e];
    uint2 w; w.x = pk2(d0, d1); w.y = pk2(d2, d3);
    *(uint2*)&cellinfo[(size_t)cell * 4] = w;
}

// ---------------- kernel 2: weights -> bf16 MFMA-fragment layout ----------
__global__ void wconv_kernel(const float* __restrict__ qkv_w,
                             const float* __restrict__ proj_w,
                             ushort_t* __restrict__ qkv_wf,
                             ushort_t* __restrict__ proj_wf) {
    int i = blockIdx.x * blockDim.x + threadIdx.x;   // (tile,ks,lane)
    int lane = i & 63, ks = (i >> 6) & 7, tile = i >> 9;
    int l15 = lane & 15, lg = lane >> 4;
    if (tile < 48) {
        const float* src = qkv_w + (size_t)(tile * 16 + l15) * 256 + ks * 32 + lg * 8;
        ushort_t* dst = qkv_wf + (size_t)i * 8;
        #pragma unroll
        for (int e = 0; e < 8; ++e) dst[e] = f2b(src[e]);
    }
    if (tile < 16) {
        const float* src = proj_w + (size_t)(tile * 16 + l15) * 256 + ks * 32 + lg * 8;
        ushort_t* dst = proj_wf + (size_t)i * 8;
        #pragma unroll
        for (int e = 0; e < 8; ++e) dst[e] = f2b(src[e]);
    }
}

// ---------------- fused kernel: one leaf block / WG, wave = head ----------
// 256 threads (4 waves), 3 blocks/CU (53 KB LDS). Wave h owns head h:
// computes q,k,v for ch [h*64,(h+1)*64) itself -> all repacks wave-private.
// LDS map:
//   [0     , 16384) xb bf16[32][256] swz8  -> xo overlay (PV out)
//   [16384 , 36864) 4 x 5120 B per-wave slot: qs chunk-frag (4 KB)
//                                             -> vs overlay [64][40] pad
//   [36864 , 53248) 4 x 4096 B per-wave slot: ks chunk-frag (4 KB)
//                                             -> comb overlay (2 KB)
#define LS_XB   0
#define LS_QV   16384
#define LS_KC   36864
#define LS_TOT  53248

__global__ __launch_bounds__(256, 3)
void fused_attn(const float* __restrict__ x,
                const ushort_t* __restrict__ qkv_wf,
                const float* __restrict__ qkv_b,
                const ushort_t* __restrict__ cellinfo,
                const ushort_t* __restrict__ proj_wf,
                const float* __restrict__ proj_b,
                const float* __restrict__ gate_w,
                const float* __restrict__ gate_b,
                float* __restrict__ out)
{
    __shared__ __align__(16) char smem[LS_TOT];
    ushort_t* xb = (ushort_t*)(smem + LS_XB);
    ushort_t* xo = (ushort_t*)(smem + LS_XB);     // overlay: xb dead post-vGEMM

    const int t = threadIdx.x;
    const int h = t >> 6, lane = t & 63, l15 = lane & 15, lg = lane >> 4;
    const int bi = blockIdx.x, mbase = bi * 32;

    ushort_t* qsw   = (ushort_t*)(smem + LS_QV + h * 5120);  // wave-private
    ushort_t* vsw   = qsw;                                   // overlay
    ushort_t* ksw   = (ushort_t*)(smem + LS_KC + h * 4096);  // wave-private
    ushort_t* combw = ksw;                                   // overlay

    // ---- P1: stage x -> bf16 LDS (swz8) ---------------------------------
    #pragma unroll
    for (int i = 0; i < 8; ++i) {
        int flat = i * 1024 + t * 4;
        int r = flat >> 8, c = flat & 255;
        float4 xv = *(const float4*)&x[(size_t)(mbase + r) * CH + c];
        uint2 wv; wv.x = pk2(xv.x, xv.y); wv.y = pk2(xv.z, xv.w);
        *(uint2*)&xb[r * 256 + (c ^ ((r & 7) << 3))] = wv;
    }
    __syncthreads();   // B1

    const int slB = (l15 & 7) << 3;

    // ---- P2: q/k GEMM (wave h: q tiles h*4+i, k tiles 16+h*4+i) ---------
    {
        f32x4 aq[4][2], ak[4][2];
        #pragma unroll
        for (int i = 0; i < 4; ++i)
            #pragma unroll
            for (int rt = 0; rt < 2; ++rt) {
                aq[i][rt] = (f32x4){0.f, 0.f, 0.f, 0.f};
                ak[i][rt] = (f32x4){0.f, 0.f, 0.f, 0.f};
            }
        #pragma unroll
        for (int ks = 0; ks < 8; ++ks) {
            int k0 = (ks * 32 + lg * 8) ^ slB;
            bf16x8 xf0 = *(const bf16x8*)&xb[l15 * 256 + k0];
            bf16x8 xf1 = *(const bf16x8*)&xb[(16 + l15) * 256 + k0];
            #pragma unroll
            for (int i = 0; i < 4; ++i) {
                bf16x8 wq = *(const bf16x8*)(qkv_wf
                              + ((size_t)((h * 4 + i) * 8 + ks)) * 512 + lane * 8);
                bf16x8 wk = *(const bf16x8*)(qkv_wf
                              + ((size_t)((16 + h * 4 + i) * 8 + ks)) * 512 + lane * 8);
                aq[i][0] = MFMA(wq, xf0, aq[i][0]);
                aq[i][1] = MFMA(wq, xf1, aq[i][1]);
                ak[i][0] = MFMA(wk, xf0, ak[i][0]);
                ak[i][1] = MFMA(wk, xf1, ak[i][1]);
            }
        }
        #pragma unroll
        for (int i = 0; i < 4; ++i) {
            f32x4 bq = *(const f32x4*)&qkv_b[(h * 4 + i) * 16 + lg * 4];
            f32x4 bk = *(const f32x4*)&qkv_b[256 + (h * 4 + i) * 16 + lg * 4];
            #pragma unroll
            for (int rt = 0; rt < 2; ++rt) {
                f32x4 vq = aq[i][rt] + bq;
                uint2 wq2; wq2.x = pk2(vq[0], vq[1]); wq2.y = pk2(vq[2], vq[3]);
                *(uint2*)&qsw[(i * 2 + rt) * 256 + lane * 4] = wq2;
                f32x4 vk = ak[i][rt] + bk;
                uint2 wk2; wk2.x = pk2(vk[0], vk[1]); wk2.y = pk2(vk[2], vk[3]);
                *(uint2*)&ksw[(i * 2 + rt) * 256 + lane * 4] = wk2;
            }
        }
    }

    // ---- P3: q/k fragment loads (wave-private; no barrier) --------------
    uint4 qld[2][2], kld[2][2];
    #pragma unroll
    for (int rt = 0; rt < 2; ++rt) {
        #pragma unroll
        for (int ks2 = 0; ks2 < 2; ++ks2) {
            int lt = ks2 * 2 + (lg >> 1);
            int a0 = (lt * 2 + rt) * 256 + ((lg & 1) * 32 + l15) * 4;
            uint2 u0 = *(const uint2*)&qsw[a0];
            uint2 u1 = *(const uint2*)&qsw[a0 + 64];
            qld[rt][ks2] = (uint4){u0.x, u0.y, u1.x, u1.y};
            uint2 w0 = *(const uint2*)&ksw[a0];
            uint2 w1 = *(const uint2*)&ksw[a0 + 64];
            kld[rt][ks2] = (uint4){w0.x, w0.y, w1.x, w1.y};
        }
    }

    // ---- P4: v GEMM (non-swapped: D[row][ch]) -> vs (overlay qs) --------
    {
        f32x4 av[4][2];
        #pragma unroll
        for (int i = 0; i < 4; ++i) {
            av[i][0] = (f32x4){0.f, 0.f, 0.f, 0.f};
            av[i][1] = (f32x4){0.f, 0.f, 0.f, 0.f};
        }
        #pragma unroll
        for (int ks = 0; ks < 8; ++ks) {
            int k0 = (ks * 32 + lg * 8) ^ slB;
            bf16x8 xf0 = *(const bf16x8*)&xb[l15 * 256 + k0];
            bf16x8 xf1 = *(const bf16x8*)&xb[(16 + l15) * 256 + k0];
            #pragma unroll
            for (int i = 0; i < 4; ++i) {
                bf16x8 wv = *(const bf16x8*)(qkv_wf
                              + ((size_t)((32 + h * 4 + i) * 8 + ks)) * 512 + lane * 8);
                av[i][0] = MFMA(xf0, wv, av[i][0]);
                av[i][1] = MFMA(xf1, wv, av[i][1]);
            }
        }
        #pragma unroll
        for (int i = 0; i < 4; ++i) {
            int vch = (h * 4 + i) * 16 + l15;        // global ch
            float bv = qkv_b[512 + vch];
            int vl = i * 16 + l15;                    // local row (pad-40)
            #pragma unroll
            for (int rt = 0; rt < 2; ++rt) {
                f32x4 v = av[i][rt];
                uint2 wv2; wv2.x = pk2(v[0] + bv, v[1] + bv);
                wv2.y = pk2(v[2] + bv, v[3] + bv);
                *(uint2*)&vsw[vl * 40 + rt * 16 + lg * 4] = wv2;
            }
        }
    }

    // ---- P5: scores MFMA (A=k M=kj, B=q N=qi) ---------------------------
    f32x4 s[2][2];
    #pragma unroll
    for (int qt = 0; qt < 2; ++qt) {
        s[qt][0] = (f32x4){0.f, 0.f, 0.f, 0.f};
        s[qt][1] = (f32x4){0.f, 0.f, 0.f, 0.f};
    }
    #pragma unroll
    for (int qt = 0; qt < 2; ++qt) {
        #pragma unroll
        for (int ks2 = 0; ks2 < 2; ++ks2) {
            bf16x8 qf = u4b8(qld[qt][ks2]);
            #pragma unroll
            for (int kt = 0; kt < 2; ++kt)
                s[qt][kt] = MFMA(u4b8(kld[kt][ks2]), qf, s[qt][kt]);
        }
    }

    // ---- P6: softmax + gate; kj=32 via mean of raw scores (linearity) ---
    const ushort_t* crow = cellinfo + (size_t)bi * 4096;
    const float gw0 = gate_w[h * 4 + 0], gw1 = gate_w[h * 4 + 1];
    const float gw2 = gate_w[h * 4 + 2], gw3 = gate_w[h * 4 + 3];
    const float gb  = gate_b[h];
    #pragma unroll
    for (int qt = 0; qt < 2; ++qt) {
        int qi = qt * 16 + l15;
        float r[8], gt[8];
        float rawsum = 0.f;
        #pragma unroll
        for (int kt = 0; kt < 2; ++kt) {
            int kj0 = kt * 16 + lg * 4;
            const uint_t* cp = (const uint_t*)(crow + ((size_t)qi * 32 + kj0) * 4);
            uint4 cA = *(const uint4*)cp;
            uint4 cB = *(const uint4*)(cp + 4);
            uint_t d01[4] = {cA.x, cA.z, cB.x, cB.z};
            uint_t d23[4] = {cA.y, cA.w, cB.y, cB.w};
            #pragma unroll
            for (int j = 0; j < 4; ++j) {
                int kj = kj0 + j;
                bool fixed = (kj == qi);
                ushort_t e3b = (ushort_t)(d23[j] >> 16);
                bool valid = (e3b != (ushort_t)0xFFFFu);
                float e3 = b2f(e3b);
                float sb = fixed ? 1.0f : (valid ? e3 : -INFINITY);
                float g;
                if (fixed)      g = gw3 + gb;
                else if (valid) g = b2f((ushort_t)(d01[j] & 0xFFFF)) * gw0
                                  + b2f((ushort_t)(d01[j] >> 16))    * gw1
                                  + b2f((ushort_t)(d23[j] & 0xFFFF)) * gw2
                                  + e3 * gw3 + gb;
                else            g = 0.0f;
                float sraw = s[qt][kt][j];
                rawsum += sraw;
                r[kt * 4 + j]  = sraw * 0.125f + sb;
                gt[kt * 4 + j] = g;
            }
        }
        rawsum += __shfl_xor(rawsum, 16);
        rawsum += __shfl_xor(rawsum, 32);
        float r2 = rawsum * (0.125f / 32.0f) + 1.0f;

        float m = fmaxf(fmaxf(fmaxf(r[0], r[1]), fmaxf(r[2], r[3])),
                        fmaxf(fmaxf(r[4], r[5]), fmaxf(r[6], r[7])));
        m = fmaxf(m, r2);
        m = fmaxf(m, __shfl_xor(m, 16));
        m = fmaxf(m, __shfl_xor(m, 32));
        float sum = 0.f;
        #pragma unroll
        for (int i = 0; i < 8; ++i) { r[i] = __expf(r[i] - m); sum += r[i]; }
        sum += __shfl_xor(sum, 16);
        sum += __shfl_xor(sum, 32);
        float e2 = __expf(r2 - m);
        float inv = 1.0f / (sum + e2);
        float comb32 = e2 * inv + (gw3 + gb);
        float cadd = comb32 * 0.03125f;     // fold kj=32 PV into every entry
        int swz = (l15 >> 2) << 3;
        #pragma unroll
        for (int kt = 0; kt < 2; ++kt) {
            int kj0 = kt * 16 + lg * 4;
            uint2 wv;
            wv.x = pk2(r[kt*4+0] * inv + gt[kt*4+0] + cadd,
                       r[kt*4+1] * inv + gt[kt*4+1] + cadd);
            wv.y = pk2(r[kt*4+2] * inv + gt[kt*4+2] + cadd,
                       r[kt*4+3] * inv + gt[kt*4+3] + cadd);
            *(uint2*)&combw[qi * 32 + (kj0 ^ swz)] = wv;
        }
    }

    // ---- P7: PV fragment loads (wave-private) ---------------------------
    bf16x8 vf[4], cfr[2];
    #pragma unroll
    for (int ct = 0; ct < 4; ++ct)
        vf[ct] = *(const bf16x8*)&vsw[(ct * 16 + l15) * 40 + lg * 8];
    #pragma unroll
    for (int qt = 0; qt < 2; ++qt) {
        int qi = qt * 16 + l15;
        int off = (lg * 8) ^ (((l15 >> 2) & 3) << 3);
        cfr[qt] = *(const bf16x8*)&combw[qi * 32 + off];
    }
    __syncthreads();   // B2: all xb reads done -> xo overlay safe

    // ---- P8: PV MFMA -> xo (xb overlay) ---------------------------------
    #pragma unroll
    for (int ct = 0; ct < 4; ++ct) {
        #pragma unroll
        for (int qt = 0; qt < 2; ++qt) {
            f32x4 acc = {0.f, 0.f, 0.f, 0.f};
            acc = MFMA(vf[ct], cfr[qt], acc);
            int qi = qt * 16 + l15;
            uint2 wv;
            wv.x = pk2(acc[0], acc[1]);
            wv.y = pk2(acc[2], acc[3]);
            int c0 = h * 64 + ct * 16 + lg * 4;
            *(uint2*)&xo[qi * 256 + (c0 ^ ((l15 & 7) << 3))] = wv;
        }
    }
    __syncthreads();   // B3: xo read cross-wave by proj

    // ---- P9: proj (wave h: tiles h, h+4, h+8, h+12) ---------------------
    {
        const int slR = (l15 & 7) << 3;
        f32x4 pacc[4][2];
        #pragma unroll
        for (int i = 0; i < 4; ++i) {
            pacc[i][0] = (f32x4){0.f, 0.f, 0.f, 0.f};
            pacc[i][1] = (f32x4){0.f, 0.f, 0.f, 0.f};
        }
        #pragma unroll
        for (int ks = 0; ks < 8; ++ks) {
            int k0 = ks * 32 + lg * 8;
            bf16x8 b0 = *(const bf16x8*)&xo[l15 * 256 + (k0 ^ slR)];
            bf16x8 b1 = *(const bf16x8*)&xo[(16 + l15) * 256 + (k0 ^ slR)];
            #pragma unroll
            for (int i = 0; i < 4; ++i) {
                int pt = h + i * 4;
                bf16x8 a = *(const bf16x8*)(proj_wf
                              + ((size_t)(pt * 8 + ks)) * 512 + lane * 8);
                pacc[i][0] = MFMA(a, b0, pacc[i][0]);
                pacc[i][1] = MFMA(a, b1, pacc[i][1]);
            }
        }
        #pragma unroll
        for (int i = 0; i < 4; ++i) {
            int pt = h + i * 4, n0 = pt * 16;
            f32x4 bv = *(const f32x4*)&proj_b[n0 + lg * 4];
            f32x4 o0 = pacc[i][0] + bv;
            f32x4 o1 = pacc[i][1] + bv;
            int c0 = n0 + lg * 4;
            *(f32x4*)&out[(size_t)(mbase + l15) * 256 + c0]      = o0;
            *(f32x4*)&out[(size_t)(mbase + 16 + l15) * 256 + c0] = o1;
        }
    }
}

extern "C" void kernel_launch(void* const* d_in, const int* in_sizes, int n_in,
                              void* d_out, int out_size, void* d_ws, size_t ws_size,
                              hipStream_t stream) {
    const float* x      = (const float*)d_in[0];
    const int*   ei     = (const int*)  d_in[1];
    const float* ev     = (const float*)d_in[2];
    const float* pos    = (const float*)d_in[3];
    const float* qkv_w  = (const float*)d_in[4];
    const float* qkv_b  = (const float*)d_in[5];
    const float* proj_w = (const float*)d_in[6];
    const float* proj_b = (const float*)d_in[7];
    const float* gate_w = (const float*)d_in[8];
    const float* gate_b = (const float*)d_in[9];
    float* out = (float*)d_out;

    const int E  = in_sizes[2];
    const int N  = in_sizes[0] / CH;
    const int nb = N / BSZ;

    char* ws = (char*)d_ws;
    int*      win      = (int*)ws;                              // nb*4096 B
    ushort_t* cellinfo = (ushort_t*)(ws + (size_t)nb * 4096);   // nb*8192 B
    size_t off = (size_t)nb * 12288;
    ushort_t* qkv_wf  = (ushort_t*)(ws + off); off += 48 * 8 * 64 * 8 * 2;
    ushort_t* proj_wf = (ushort_t*)(ws + off); off += 16 * 8 * 64 * 8 * 2;

    // one memset covers win (-1) and cellinfo (NaN sentinel) — both 0xFF
    hipMemsetAsync(ws, 0xFF, (size_t)nb * 12288, stream);
    edge_win_kernel<<<(E + 255) / 256, 256, 0, stream>>>(ei, E, nb, win);
    edge_feat_kernel<<<(E + 255) / 256, 256, 0, stream>>>(ei, ev, pos, win, E,
                                                          cellinfo);
    wconv_kernel<<<96, 256, 0, stream>>>(qkv_w, proj_w, qkv_wf, proj_wf);
    fused_attn<<<nb, 256, 0, stream>>>(x, qkv_wf, qkv_b, cellinfo,
                                       proj_wf, proj_b, gate_w, gate_b, out);
}

// Round 9
// 262.753 us; speedup vs baseline: 1.1978x; 1.1978x over previous
//
#include <hip/hip_runtime.h>
#include <math.h>

#define BSZ 32
#define CH  256

typedef short  bf16x8 __attribute__((ext_vector_type(8)));
typedef float  f32x4  __attribute__((ext_vector_type(4)));
typedef unsigned short ushort_t;
typedef unsigned int   uint_t;

#define MFMA(a, b, c) __builtin_amdgcn_mfma_f32_16x16x32_bf16((a), (b), (c), 0, 0, 0)

__device__ __forceinline__ ushort_t f2b(float f) {
    uint_t u = __builtin_bit_cast(uint_t, f);
    uint_t r = (u + 0x7FFFu + ((u >> 16) & 1u)) >> 16;   // RTNE
    return (ushort_t)r;
}
__device__ __forceinline__ float b2f(ushort_t u) {
    uint_t v = ((uint_t)u) << 16;
    return __builtin_bit_cast(float, v);
}
__device__ __forceinline__ uint_t pk2(float a, float b) {
    return (uint_t)f2b(a) | ((uint_t)f2b(b) << 16);
}
__device__ __forceinline__ bf16x8 u4b8(uint4 u) {
    return __builtin_bit_cast(bf16x8, u);
}

// ---------------- kernel 1: per-cell winning edge (last write wins) -------
__global__ void edge_win_kernel(const int* __restrict__ ei, int E, int nb,
                                int* __restrict__ win) {
    int e = blockIdx.x * blockDim.x + threadIdx.x;
    if (e >= E) return;
    int r = ei[e];
    int c = ei[E + e];
    int br = r >> 5, bc = c >> 5;
    if (br == bc && br < nb) {
        atomicMax(&win[br * (BSZ * BSZ) + (r & 31) * BSZ + (c & 31)], e);
    }
}

// ---------------- kernel 1b: winning edges scatter their features ---------
__global__ void edge_feat_kernel(const int* __restrict__ ei,
                                 const float* __restrict__ ev,
                                 const float* __restrict__ pos,
                                 const int* __restrict__ win, int E,
                                 ushort_t* __restrict__ cellinfo) {
    int e = blockIdx.x * blockDim.x + threadIdx.x;
    if (e >= E) return;
    int r = ei[e];
    int c = ei[E + e];
    int br = r >> 5, bc = c >> 5;
    if (br != bc) return;
    int cell = br * 1024 + (r & 31) * 32 + (c & 31);
    if (win[cell] != e) return;
    float d0 = pos[c * 3 + 0] - pos[r * 3 + 0];
    float d1 = pos[c * 3 + 1] - pos[r * 3 + 1];
    float d2 = pos[c * 3 + 2] - pos[r * 3 + 2];
    float d3 = ev[e];
    uint2 w; w.x = pk2(d0, d1); w.y = pk2(d2, d3);
    *(uint2*)&cellinfo[(size_t)cell * 4] = w;
}

// ---------------- kernel 2: weights -> bf16 MFMA-fragment layout ----------
__global__ void wconv_kernel(const float* __restrict__ qkv_w,
                             const float* __restrict__ proj_w,
                             ushort_t* __restrict__ qkv_wf,
                             ushort_t* __restrict__ proj_wf) {
    int i = blockIdx.x * blockDim.x + threadIdx.x;   // (tile,ks,lane)
    int lane = i & 63, ks = (i >> 6) & 7, tile = i >> 9;
    int l15 = lane & 15, lg = lane >> 4;
    if (tile < 48) {
        const float* src = qkv_w + (size_t)(tile * 16 + l15) * 256 + ks * 32 + lg * 8;
        ushort_t* dst = qkv_wf + (size_t)i * 8;
        #pragma unroll
        for (int e = 0; e < 8; ++e) dst[e] = f2b(src[e]);
    }
    if (tile < 16) {
        const float* src = proj_w + (size_t)(tile * 16 + l15) * 256 + ks * 32 + lg * 8;
        ushort_t* dst = proj_wf + (size_t)i * 8;
        #pragma unroll
        for (int e = 0; e < 8; ++e) dst[e] = f2b(src[e]);
    }
}

// ---------------- fused kernel: qkv GEMM + attention + proj ---------------
// BM=64 (2 leaves), 512 threads, 1 WG/CU (128 KiB LDS).
//   [0      ,  32768) xb  bf16[64][256] swz8   -> comb overlay (16 KiB)
//   [32768  ,  65536) qs  chunk-frag [2][8192] -> xo overlay
//   [65536  ,  98304) ksm chunk-frag [2][8192]
//   [98304  , 131072) vs  vT [2][256ch][32row], XOR swz ((ch&3)<<3)
#define LS_XB   0
#define LS_QS   32768
#define LS_KS   65536
#define LS_VS   98304
#define LS_TOT  131072

__global__ __launch_bounds__(512, 2)
void fused_attn(const float* __restrict__ x,
                const ushort_t* __restrict__ qkv_wf,
                const float* __restrict__ qkv_b,
                const ushort_t* __restrict__ cellinfo,
                const ushort_t* __restrict__ proj_wf,
                const float* __restrict__ proj_b,
                const float* __restrict__ gate_w,
                const float* __restrict__ gate_b,
                float* __restrict__ out)
{
    __shared__ __align__(16) char smem[LS_TOT];
    ushort_t* xb   = (ushort_t*)(smem + LS_XB);
    ushort_t* comb = (ushort_t*)(smem + LS_XB);   // overlay (xb dead post-B2)
    ushort_t* qs   = (ushort_t*)(smem + LS_QS);
    ushort_t* xo   = (ushort_t*)(smem + LS_QS);   // overlay (qs dead post-B2b)
    ushort_t* ksm  = (ushort_t*)(smem + LS_KS);
    ushort_t* vs   = (ushort_t*)(smem + LS_VS);

    const int t = threadIdx.x;
    const int w = t >> 6, lane = t & 63, l15 = lane & 15, lg = lane >> 4;
    const int bi = blockIdx.x;
    const int mbase = bi * 64;

    // ---- P1: stage x -> bf16 LDS (swz8) ---------------------------------
    #pragma unroll
    for (int i = 0; i < 8; ++i) {
        int flat = i * 2048 + t * 4;
        int r = flat >> 8, c = flat & 255;
        float4 xv = *(const float4*)&x[(size_t)(mbase + r) * CH + c];
        uint2 wv; wv.x = pk2(xv.x, xv.y); wv.y = pk2(xv.z, xv.w);
        *(uint2*)&xb[r * 256 + (c ^ ((r & 7) << 3))] = wv;
    }
    __syncthreads();   // B1

    // ---- P2: qkv GEMM, 2-deep ping-pong pipeline ------------------------
    // wave w owns ch-tiles it*8+w (it 0,1=q; 2,3=k; 4,5=v)
    const int slB = (l15 & 7) << 3;
    f32x4 acc[6][4];
    #pragma unroll
    for (int it = 0; it < 6; ++it)
        #pragma unroll
        for (int m = 0; m < 4; ++m) acc[it][m] = (f32x4){0.f, 0.f, 0.f, 0.f};

    bf16x8 xfA[4], xfB[4], wfA[6], wfB[6];

#define LOADX(dst, kss) { int k0_ = ((kss) * 32 + lg * 8) ^ slB;              \
        dst[0] = *(const bf16x8*)&xb[l15 * 256 + k0_];                        \
        dst[1] = *(const bf16x8*)&xb[(16 + l15) * 256 + k0_];                 \
        dst[2] = *(const bf16x8*)&xb[(32 + l15) * 256 + k0_];                 \
        dst[3] = *(const bf16x8*)&xb[(48 + l15) * 256 + k0_]; }

#define LOADW(dst, kss) { _Pragma("unroll")                                   \
        for (int it_ = 0; it_ < 6; ++it_)                                     \
            dst[it_] = *(const bf16x8*)(qkv_wf                                \
                + ((size_t)(((it_ * 8 + w) * 8) + (kss))) * 512 + lane * 8); }

#define COMPUTE(xf, wf) { _Pragma("unroll")                                   \
        for (int it_ = 0; it_ < 6; ++it_) {                                   \
            if (it_ < 4) { _Pragma("unroll")                                  \
                for (int m_ = 0; m_ < 4; ++m_)                                \
                    acc[it_][m_] = MFMA(wf[it_], xf[m_], acc[it_][m_]);       \
            } else { _Pragma("unroll")                                        \
                for (int m_ = 0; m_ < 4; ++m_)                                \
                    acc[it_][m_] = MFMA(xf[m_], wf[it_], acc[it_][m_]); } } }

    LOADX(xfA, 0); LOADW(wfA, 0);
    LOADX(xfB, 1); LOADW(wfB, 1);
    COMPUTE(xfA, wfA);                      // ks=0
    LOADX(xfA, 2); LOADW(wfA, 2);
    COMPUTE(xfB, wfB);                      // ks=1
    LOADX(xfB, 3); LOADW(wfB, 3);
    COMPUTE(xfA, wfA);                      // ks=2
    LOADX(xfA, 4); LOADW(wfA, 4);
    COMPUTE(xfB, wfB);                      // ks=3
    LOADX(xfB, 5); LOADW(wfB, 5);
    COMPUTE(xfA, wfA);                      // ks=4
    LOADX(xfA, 6); LOADW(wfA, 6);
    COMPUTE(xfB, wfB);                      // ks=5
    LOADX(xfB, 7); LOADW(wfB, 7);
    COMPUTE(xfA, wfA);                      // ks=6
    COMPUTE(xfB, wfB);                      // ks=7

    // stores: q -> qs, k -> ksm (chunk layout), v -> vs (vT + XOR swz)
    #pragma unroll
    for (int it = 0; it < 6; ++it) {
        int tt = it * 8 + w;
        if (it < 4) {
            f32x4 bv4 = *(const f32x4*)&qkv_b[tt * 16 + lg * 4];
            ushort_t* dst = (it < 2) ? qs : ksm;
            int tloc = (it < 2) ? tt : tt - 16;
            #pragma unroll
            for (int m = 0; m < 4; ++m) {
                f32x4 v = acc[it][m] + bv4;
                uint2 wv; wv.x = pk2(v[0], v[1]); wv.y = pk2(v[2], v[3]);
                int g = m >> 1;
                *(uint2*)&dst[g * 8192 + (tloc * 2 + (m & 1)) * 256 + lane * 4] = wv;
            }
        } else {
            int vch = (tt - 32) * 16 + l15;
            float bv = qkv_b[512 + vch];
            int swzv = (vch & 3) << 3;
            #pragma unroll
            for (int m = 0; m < 4; ++m) {
                f32x4 v = acc[it][m];
                uint2 wv; wv.x = pk2(v[0] + bv, v[1] + bv);
                wv.y = pk2(v[2] + bv, v[3] + bv);
                int g = m >> 1;
                int roff = ((m & 1) * 16 + lg * 4) ^ swzv;
                *(uint2*)&vs[g * 8192 + vch * 32 + roff] = wv;
            }
        }
    }

    // ---- cellinfo preload (global; hides latency under the barrier) -----
    const int gl = w >> 2, h = w & 3;
    const ushort_t* crow = cellinfo + (size_t)(bi * 2 + gl) * 4096;
    uint4 cellA[2][2], cellB[2][2];
    #pragma unroll
    for (int qt = 0; qt < 2; ++qt) {
        int qi = qt * 16 + l15;
        #pragma unroll
        for (int kt = 0; kt < 2; ++kt) {
            int kj0 = kt * 16 + lg * 4;
            const uint_t* cp = (const uint_t*)(crow + ((size_t)qi * 32 + kj0) * 4);
            cellA[qt][kt] = *(const uint4*)cp;
            cellB[qt][kt] = *(const uint4*)(cp + 4);
        }
    }
    const float gw0 = gate_w[h * 4 + 0], gw1 = gate_w[h * 4 + 1];
    const float gw2 = gate_w[h * 4 + 2], gw3 = gate_w[h * 4 + 3];
    const float gb  = gate_b[h];

    __syncthreads();   // B2: qkv LDS stores visible; xb dead from here

    // ---- P3: fragment loads (LDS) ---------------------------------------
    uint4 qld[2][2], kld[2][2];
    #pragma unroll
    for (int rt = 0; rt < 2; ++rt) {
        #pragma unroll
        for (int ks2 = 0; ks2 < 2; ++ks2) {
            int ttq = h * 4 + ks2 * 2 + (lg >> 1);
            int a0 = gl * 8192 + (ttq * 2 + rt) * 256 + ((lg & 1) * 32 + l15) * 4;
            uint2 u0 = *(const uint2*)&qs[a0];
            uint2 u1 = *(const uint2*)&qs[a0 + 64];
            qld[rt][ks2] = (uint4){u0.x, u0.y, u1.x, u1.y};
            uint2 w0 = *(const uint2*)&ksm[a0];
            uint2 w1 = *(const uint2*)&ksm[a0 + 64];
            kld[rt][ks2] = (uint4){w0.x, w0.y, w1.x, w1.y};
        }
    }
    bf16x8 vf[4];
    #pragma unroll
    for (int ct = 0; ct < 4; ++ct) {
        int off = (lg * 8) ^ ((l15 & 3) << 3);
        vf[ct] = *(const bf16x8*)&vs[gl * 8192
                                     + (h * 64 + ct * 16 + l15) * 32 + off];
    }
    __syncthreads();   // B2b: all qs/ksm reads done -> xo overlay safe

    // ---- P4: scores MFMA (A=k M=kj, B=q N=qi) ---------------------------
    f32x4 s[2][2];
    #pragma unroll
    for (int qt = 0; qt < 2; ++qt) {
        s[qt][0] = (f32x4){0.f, 0.f, 0.f, 0.f};
        s[qt][1] = (f32x4){0.f, 0.f, 0.f, 0.f};
    }
    #pragma unroll
    for (int qt = 0; qt < 2; ++qt) {
        #pragma unroll
        for (int ks2 = 0; ks2 < 2; ++ks2) {
            bf16x8 qf = u4b8(qld[qt][ks2]);
            #pragma unroll
            for (int kt = 0; kt < 2; ++kt)
                s[qt][kt] = MFMA(u4b8(kld[kt][ks2]), qf, s[qt][kt]);
        }
    }

    // ---- P5: softmax + gate; kj=32 via mean of raw scores ---------------
    #pragma unroll
    for (int qt = 0; qt < 2; ++qt) {
        int qi = qt * 16 + l15;
        float r[8], gt[8];
        float rawsum = 0.f;
        #pragma unroll
        for (int kt = 0; kt < 2; ++kt) {
            int kj0 = kt * 16 + lg * 4;
            uint4 cA = cellA[qt][kt], cB = cellB[qt][kt];
            uint_t d01[4] = {cA.x, cA.z, cB.x, cB.z};
            uint_t d23[4] = {cA.y, cA.w, cB.y, cB.w};
            #pragma unroll
            for (int j = 0; j < 4; ++j) {
                int kj = kj0 + j;
                bool fixed = (kj == qi);
                ushort_t e3b = (ushort_t)(d23[j] >> 16);
                bool valid = (e3b != (ushort_t)0xFFFFu);
                float e3 = b2f(e3b);
                float sb = fixed ? 1.0f : (valid ? e3 : -INFINITY);
                float g;
                if (fixed)      g = gw3 + gb;
                else if (valid) g = b2f((ushort_t)(d01[j] & 0xFFFF)) * gw0
                                  + b2f((ushort_t)(d01[j] >> 16))    * gw1
                                  + b2f((ushort_t)(d23[j] & 0xFFFF)) * gw2
                                  + e3 * gw3 + gb;
                else            g = 0.0f;
                float sraw = s[qt][kt][j];
                rawsum += sraw;
                r[kt * 4 + j]  = sraw * 0.125f + sb;
                gt[kt * 4 + j] = g;
            }
        }
        rawsum += __shfl_xor(rawsum, 16);
        rawsum += __shfl_xor(rawsum, 32);
        float r2 = rawsum * (0.125f / 32.0f) + 1.0f;

        float m = fmaxf(fmaxf(fmaxf(r[0], r[1]), fmaxf(r[2], r[3])),
                        fmaxf(fmaxf(r[4], r[5]), fmaxf(r[6], r[7])));
        m = fmaxf(m, r2);
        m = fmaxf(m, __shfl_xor(m, 16));
        m = fmaxf(m, __shfl_xor(m, 32));
        float sum = 0.f;
        #pragma unroll
        for (int i = 0; i < 8; ++i) { r[i] = __expf(r[i] - m); sum += r[i]; }
        sum += __shfl_xor(sum, 16);
        sum += __shfl_xor(sum, 32);
        float e2 = __expf(r2 - m);
        float inv = 1.0f / (sum + e2);
        float comb32 = e2 * inv + (gw3 + gb);
        float cadd = comb32 * 0.03125f;     // fold kj=32 PV into every entry
        int swz = (l15 & 3) << 3;
        #pragma unroll
        for (int kt = 0; kt < 2; ++kt) {
            int kj0 = kt * 16 + lg * 4;
            uint2 wv;
            wv.x = pk2(r[kt*4+0] * inv + gt[kt*4+0] + cadd,
                       r[kt*4+1] * inv + gt[kt*4+1] + cadd);
            wv.y = pk2(r[kt*4+2] * inv + gt[kt*4+2] + cadd,
                       r[kt*4+3] * inv + gt[kt*4+3] + cadd);
            *(uint2*)&comb[(gl * 4 + h) * 1024 + qi * 32 + (kj0 ^ swz)] = wv;
        }
    }
    // comb is wave-private -> no barrier

    // ---- P6: PV MFMA (A=vT M=c, B=comb N=qi) -> xo ----------------------
    bf16x8 cfr[2];
    #pragma unroll
    for (int qt = 0; qt < 2; ++qt) {
        int qi = qt * 16 + l15;
        int off = (lg * 8) ^ ((l15 & 3) << 3);
        cfr[qt] = *(const bf16x8*)&comb[(gl * 4 + h) * 1024 + qi * 32 + off];
    }
    #pragma unroll
    for (int ct = 0; ct < 4; ++ct) {
        #pragma unroll
        for (int qt = 0; qt < 2; ++qt) {
            f32x4 acc2 = {0.f, 0.f, 0.f, 0.f};
            acc2 = MFMA(vf[ct], cfr[qt], acc2);
            int qi = qt * 16 + l15;
            uint2 wv;
            wv.x = pk2(acc2[0], acc2[1]);
            wv.y = pk2(acc2[2], acc2[3]);
            int c0 = h * 64 + ct * 16 + lg * 4;
            *(uint2*)&xo[gl * 8192 + qi * 256 + (c0 ^ ((l15 & 7) << 3))] = wv;
        }
    }
    __syncthreads();   // B3: xo read cross-wave by proj

    // ---- P7: proj, 2 out-ch tiles per wave (no dup), preloaded weights --
    {
        const int slR = (l15 & 7) << 3;
        bf16x8 pw[2][8];
        #pragma unroll
        for (int i = 0; i < 2; ++i) {
            int pt = w * 2 + i;
            #pragma unroll
            for (int ks = 0; ks < 8; ++ks)
                pw[i][ks] = *(const bf16x8*)(proj_wf
                               + ((size_t)(pt * 8 + ks)) * 512 + lane * 8);
        }
        f32x4 pacc[2][4];
        #pragma unroll
        for (int i = 0; i < 2; ++i)
            #pragma unroll
            for (int rt = 0; rt < 4; ++rt) pacc[i][rt] = (f32x4){0.f,0.f,0.f,0.f};
        #pragma unroll
        for (int ks = 0; ks < 8; ++ks) {
            int k0 = ks * 32 + lg * 8;
            #pragma unroll
            for (int rt = 0; rt < 4; ++rt) {
                bf16x8 bfr = *(const bf16x8*)&xo[(rt >> 1) * 8192
                                 + ((rt & 1) * 16 + l15) * 256 + (k0 ^ slR)];
                pacc[0][rt] = MFMA(pw[0][ks], bfr, pacc[0][rt]);
                pacc[1][rt] = MFMA(pw[1][ks], bfr, pacc[1][rt]);
            }
        }
        #pragma unroll
        for (int i = 0; i < 2; ++i) {
            int pt = w * 2 + i, n0 = pt * 16;
            f32x4 bv = *(const f32x4*)&proj_b[n0 + lg * 4];
            #pragma unroll
            for (int rt = 0; rt < 4; ++rt) {
                f32x4 o = pacc[i][rt] + bv;
                int row = mbase + (rt >> 1) * 32 + (rt & 1) * 16 + l15;
                *(f32x4*)&out[(size_t)row * 256 + n0 + lg * 4] = o;
            }
        }
    }
}

extern "C" void kernel_launch(void* const* d_in, const int* in_sizes, int n_in,
                              void* d_out, int out_size, void* d_ws, size_t ws_size,
                              hipStream_t stream) {
    const float* x      = (const float*)d_in[0];
    const int*   ei     = (const int*)  d_in[1];
    const float* ev     = (const float*)d_in[2];
    const float* pos    = (const float*)d_in[3];
    const float* qkv_w  = (const float*)d_in[4];
    const float* qkv_b  = (const float*)d_in[5];
    const float* proj_w = (const float*)d_in[6];
    const float* proj_b = (const float*)d_in[7];
    const float* gate_w = (const float*)d_in[8];
    const float* gate_b = (const float*)d_in[9];
    float* out = (float*)d_out;

    const int E  = in_sizes[2];
    const int N  = in_sizes[0] / CH;
    const int nb = N / BSZ;

    char* ws = (char*)d_ws;
    int*      win      = (int*)ws;                              // nb*4096 B
    ushort_t* cellinfo = (ushort_t*)(ws + (size_t)nb * 4096);   // nb*8192 B
    size_t off = (size_t)nb * 12288;
    ushort_t* qkv_wf  = (ushort_t*)(ws + off); off += 48 * 8 * 64 * 8 * 2;
    ushort_t* proj_wf = (ushort_t*)(ws + off); off += 16 * 8 * 64 * 8 * 2;

    // one memset covers win (-1) and cellinfo (NaN sentinel) — both 0xFF
    hipMemsetAsync(ws, 0xFF, (size_t)nb * 12288, stream);
    edge_win_kernel<<<(E + 255) / 256, 256, 0, stream>>>(ei, E, nb, win);
    edge_feat_kernel<<<(E + 255) / 256, 256, 0, stream>>>(ei, ev, pos, win, E,
                                                          cellinfo);
    wconv_kernel<<<96, 256, 0, stream>>>(qkv_w, proj_w, qkv_wf, proj_wf);
    fused_attn<<<nb / 2, 512, 0, stream>>>(x, qkv_wf, qkv_b, cellinfo,
                                           proj_wf, proj_b, gate_w, gate_b, out);
}